// Round 4
// baseline (2094.023 us; speedup 1.0000x reference)
//
#include <hip/hip_runtime.h>
#include <hip/hip_bf16.h>
#include <math.h>

// ---------------- problem constants ----------------
#define TT   128      // timesteps
#define BB   128      // batch
#define UU   512      // LSTM units
#define EMBD 300      // embedding dim
#define EMBP 320      // padded embedding dim (multiple of 32 for MFMA K)
#define NBLK 192      // 2 dir x 3 layers x 32 column-blocks (1 block/CU, 16 h-cols each)
#define DBLK 96       // blocks per direction
#define NTHR 512      // 8 waves = (2 M-half) x (4 K-quarter); B held in VGPRs
#define BTS  1032     // Bt row stride (elements) during one-time staging

using bf16x8 = __attribute__((ext_vector_type(8))) short;
using f32x4  = __attribute__((ext_vector_type(4))) float;

// ws layout: flags 768B | epoch @4096 | X 10MB | H 6 slots (write-once!) | hf
#define NEED_WS 111681536ull
static void* g_pool = nullptr;
__attribute__((constructor)) static void alloc_pool() {
    if (hipMalloc(&g_pool, 120ull * 1024ull * 1024ull) != hipSuccess) g_pool = nullptr;
}

__device__ __forceinline__ float b2f(unsigned short u) {
    union { unsigned int i; float f; } v; v.i = ((unsigned int)u) << 16; return v.f;
}
__device__ __forceinline__ unsigned short f2b(float f) {
    union { unsigned int i; float f; } v; v.f = f;
    unsigned int i = v.i;
    return (unsigned short)((i + 0x7fffu + ((i >> 16) & 1u)) >> 16);  // RNE
}
__device__ __forceinline__ unsigned short ld_bf(const void* p, size_t i, int f32) {
    return f32 ? f2b(((const float*)p)[i]) : ((const unsigned short*)p)[i];
}
__device__ __forceinline__ float ld_f(const void* p, size_t i, int f32) {
    return f32 ? ((const float*)p)[i] : b2f(((const unsigned short*)p)[i]);
}
__device__ __forceinline__ float clampz(float x) {
    return fminf(fmaxf(x, -60.0f), 60.0f);
}
__device__ __forceinline__ float sigm(float x)  { return 1.0f / (1.0f + __expf(-x)); }
__device__ __forceinline__ float ssign(float x) { return x / (1.0f + fabsf(x)); }

__device__ __forceinline__ int detect_f32(const void* emb) {
    const unsigned int* w = (const unsigned int*)emb;
    int cnt = 0;
    #pragma unroll
    for (int i = 0; i < 64; ++i) {
        unsigned int e = (w[i] >> 23) & 0xFFu;
        cnt += (e >= 96u && e <= 159u) ? 1 : 0;
    }
    return cnt >= 48;
}

struct P {
    const int* ids;
    const void* emb;
    const void* Wm[2][3];
    const void* Um[2][3];
    const void* bm[2][3];
    const void *d0W, *d0b;
    const void *bn_gamma, *bn_beta, *bn_mean, *bn_var;
    const void *alpha, *d1W, *d1b;
    unsigned short* X;      // [TT][BB][EMBP] bf16 (written once, fence-full barrier after)
    unsigned short* H;      // [3 slots][2 dirs][TT][BB][UU] bf16 — WRITE-ONCE, write-through
    float* hf;              // [2][BB][UU] fp32 — write-through
    unsigned int* flags;    // [NBLK] per-block generation flags
    unsigned int* epoch;    // epoch[0]=dir0, epoch[64]=dir1 (separate lines)
    float* out;             // [BB][7] fp32
};

#define EPOFF 64   // dir1 epoch word offset (256 B from dir0)

__device__ __forceinline__ unsigned int ald(const unsigned int* a) {
    return __hip_atomic_load(a, __ATOMIC_RELAXED, __HIP_MEMORY_SCOPE_AGENT);
}
__device__ __forceinline__ void ast(unsigned int* a, unsigned int v) {
    __hip_atomic_store(a, v, __ATOMIC_RELAXED, __HIP_MEMORY_SCOPE_AGENT);
}

// fence-FULL flat barrier (phase 0 only; X uses normal cached stores)
__device__ __forceinline__ void gsync_fence(unsigned int* flags, unsigned int gen) {
    __syncthreads();
    if (threadIdx.x == 0) {
        __threadfence();
        ast(&flags[blockIdx.x], gen);
    }
    if (threadIdx.x < 64) {
        const int i = threadIdx.x;
        for (;;) {
            bool ok = true;
            #pragma unroll
            for (int j = 0; j < NBLK / 64; ++j)
                ok = ok && (ald(&flags[i + j * 64]) >= gen);
            if (__all(ok)) break;
            __builtin_amdgcn_s_sleep(1);
        }
        __threadfence();
    }
    __syncthreads();
}

// Two-level aggregated per-direction barrier (fence-free; data is
// write-through + write-once). Leaves store own flag; the direction's
// aggregator block polls its 96 flags and publishes one epoch word;
// everyone polls that single word (same-address broadcast load).
__device__ __forceinline__ void gsync_dir(P& p, int dirbase, int eidx, int isagg, unsigned int gen) {
    __syncthreads();
    if (threadIdx.x == 0)
        ast(&p.flags[blockIdx.x], gen);
    if (isagg && threadIdx.x < 64) {
        const unsigned int* f = p.flags + dirbase + threadIdx.x;
        const bool two = (threadIdx.x < DBLK - 64);
        for (;;) {
            bool ok = (ald(f) >= gen) && (!two || (ald(f + 64) >= gen));
            if (__all(ok)) break;
            __builtin_amdgcn_s_sleep(1);
        }
        if (threadIdx.x == 0)
            ast(&p.epoch[eidx], gen);
    }
    if (threadIdx.x < 64) {
        const unsigned int* e = &p.epoch[eidx];
        while (ald(e) < gen) __builtin_amdgcn_s_sleep(1);
    }
    __syncthreads();
}

// full-grid aggregated barrier (before head)
__device__ __forceinline__ void gsync_all(P& p, int dirbase, int eidx, int isagg, unsigned int gen) {
    __syncthreads();
    if (threadIdx.x == 0)
        ast(&p.flags[blockIdx.x], gen);
    if (isagg && threadIdx.x < 64) {
        const unsigned int* f = p.flags + dirbase + threadIdx.x;
        const bool two = (threadIdx.x < DBLK - 64);
        for (;;) {
            bool ok = (ald(f) >= gen) && (!two || (ald(f + 64) >= gen));
            if (__all(ok)) break;
            __builtin_amdgcn_s_sleep(1);
        }
        if (threadIdx.x == 0)
            ast(&p.epoch[eidx], gen);
    }
    if (threadIdx.x < 64) {
        while (!((ald(&p.epoch[0]) >= gen) && (ald(&p.epoch[EPOFF]) >= gen)))
            __builtin_amdgcn_s_sleep(1);
    }
    __syncthreads();
}

// zpart layout: [128 rows][260 f32 stride]: row r, gate-col n (0..63), kq:
//   zpart[r*260 + n*4 + kq]   (16B-aligned f32x4 per (r,n))
#define ZSTR 260

__global__ __launch_bounds__(NTHR, 2) void bilstm_persistent(P p) {
    const int blk = blockIdx.x;
    const int tid = threadIdx.x;

    const int f32 = detect_f32(p.emb);
    unsigned int gen = 0;

    // union: Bt [64][BTS] u16 (132,096 B, staging only) / zpart [128][ZSTR] f32 (133,120 B)
    __shared__ __align__(16) float smem[128 * ZSTR];
    __shared__ float hact[256];
    __shared__ float lgts[8];
    unsigned short* Bt = (unsigned short*)smem;
    float* zpart = smem;

    // ---------------- phase 0: embedding gather (normal stores) ----------------
    for (int row = blk; row < TT * BB; row += NBLK) {
        int t = row >> 7, b = row & 127;
        int id = p.ids[b * TT + t];
        unsigned short* xr = p.X + (size_t)row * EMBP;
        for (int k2 = tid; k2 < EMBP; k2 += NTHR)
            xr[k2] = (k2 < EMBD) ? ld_bf(p.emb, (size_t)id * EMBD + k2, f32)
                                 : (unsigned short)0;
    }
    gsync_fence(p.flags, ++gen);             // only fence-full barrier in the kernel

    // block responsibilities: dir, layer (wavefront-pipelined), 16 h-cols, M=128
    const int dir     = (blk >= DBLK) ? 1 : 0;
    const int rb      = blk - dir * DBLK;
    const int layer   = rb >> 5;             // 0,1,2
    const int dirbase = dir * DBLK;
    const int eidx    = dir * EPOFF;
    const int isagg   = (rb == 0);
    const int j0      = (rb & 31) * 16;      // 16 h-cols per block

    const int wv   = tid >> 6;               // wave 0..7
    const int lane = tid & 63;
    const int l15  = lane & 15;
    const int quad = lane >> 4;
    const int ko   = quad * 8;

    const int kq   = wv & 3;                 // K-quarter (256 of 1024; A1=kq0/1, A2=kq2/3)
    const int mh   = wv >> 2;                // M-half (64 rows)

    // gate-phase mapping: row gr = tid&127, 4 h-cols ct4*4 .. +3
    const int gr   = tid & 127;
    const int ct4  = tid >> 7;

    float cS[4] = {0.f, 0.f, 0.f, 0.f};     // cell state: 4 h-cells per thread

    const size_t seq = (size_t)TT * BB * UU;

    // ---- stage B panel (64 gate-columns, K=1024 padded) into LDS — ONCE ----
    // Bt k-rows: [0,KW) from W, [KW,512) zero, [512,1024) from U.
    const int KW = (layer == 0) ? EMBD : UU;
    const void* Wmat = p.Wm[dir][layer];
    const void* Umat = p.Um[dir][layer];
    const void* bias = p.bm[dir][layer];
    {
        int n = tid >> 3, ks = tid & 7;                          // 8 threads per gate-col row
        int wcol = ((n >> 2) & 3) * UU + j0 + (n >> 4) * 4 + (n & 3);  // gate*512 + j0 + ct*4 + jj
        for (int k2 = ks; k2 < 1024; k2 += 8) {
            unsigned short v;
            if (k2 < KW)        v = ld_bf(Wmat, (size_t)k2 * 2048 + wcol, f32);
            else if (k2 < 512)  v = 0;
            else                v = ld_bf(Umat, (size_t)(k2 - 512) * 2048 + wcol, f32);
            Bt[n * BTS + k2] = v;
        }
    }
    // gate-phase bias (per thread: 4 gates x 4 local h-cols)
    float bz[4][4];
    #pragma unroll
    for (int g = 0; g < 4; ++g)
        #pragma unroll
        for (int jj = 0; jj < 4; ++jj)
            bz[g][jj] = ld_f(bias, g * UU + j0 + ct4 * 4 + jj, f32);
    __syncthreads();

    // ---- load this wave's B fragments into REGISTERS (128 VGPR), Bt then dead ----
    bf16x8 breg[8][4];
    #pragma unroll
    for (int kt = 0; kt < 8; ++kt)
        #pragma unroll
        for (int ct = 0; ct < 4; ++ct)
            breg[kt][ct] = *(const bf16x8*)&Bt[(ct * 16 + l15) * BTS + (kq * 8 + kt) * 32 + ko];
    __syncthreads();   // Bt dead; smem becomes zpart

    // per-wave A k-offsets within its panel (zero-B tiles of layer0 clamp to 0)
    int koff[8];
    if (kq < 2) {
        if (layer == 0) {
            #pragma unroll
            for (int kt = 0; kt < 8; ++kt) {
                int tk = kq * 8 + kt;
                koff[kt] = (tk < 10) ? tk * 32 : 0;   // B==0 for k>=320: any valid addr
            }
        } else {
            #pragma unroll
            for (int kt = 0; kt < 8; ++kt) koff[kt] = kq * 256 + kt * 32;
        }
    } else {
        #pragma unroll
        for (int kt = 0; kt < 8; ++kt) koff[kt] = (kq - 2) * 256 + kt * 32;
    }

    // write-once slots: layer l writes slot l, reads slot l-1
    unsigned short*       Hl  = p.H + (size_t)(layer * 2 + dir) * seq;
    const unsigned short* Hin = (layer > 0) ? (p.H + (size_t)((layer - 1) * 2 + dir) * seq) : nullptr;

    // ---------------- wavefront-pipelined step loop: 130 barriers/dir ----------------
    for (int s = 0; s < TT + 2; ++s) {
        const int t = s - layer;             // this layer's timestep at wavefront step s
        const bool tv = (t >= 0 && t < TT);

        if (tv) {
            // ---- MFMA: z-partial for this wave's (64 rows x 64 cols x K-quarter) ----
            const unsigned short* Abase = nullptr;
            int astr = 0;
            if (kq < 2) {                    // input contribution (always present)
                if (layer == 0) {
                    int tx = dir ? (TT - 1 - t) : t;
                    Abase = p.X + (size_t)tx * BB * EMBP;  astr = EMBP;
                } else {
                    Abase = Hin + (size_t)t * BB * UU;     astr = UU;
                }
            } else if (t > 0) {              // recurrent contribution
                Abase = Hl + (size_t)(t - 1) * BB * UU;    astr = UU;
            }
            if (Abase) {
                #pragma unroll
                for (int rt = 0; rt < 4; ++rt) {
                    const unsigned short* ap =
                        Abase + (size_t)(mh * 64 + rt * 16 + l15) * astr + ko;
                    bf16x8 av[8];
                    #pragma unroll
                    for (int kt = 0; kt < 8; ++kt)
                        av[kt] = *(const bf16x8*)(ap + koff[kt]);
                    f32x4 acc[4];
                    #pragma unroll
                    for (int ct = 0; ct < 4; ++ct) acc[ct] = f32x4{0.f, 0.f, 0.f, 0.f};
                    #pragma unroll
                    for (int kt = 0; kt < 8; ++kt)
                        #pragma unroll
                        for (int ct = 0; ct < 4; ++ct)
                            acc[ct] = __builtin_amdgcn_mfma_f32_16x16x32_bf16(
                                av[kt], breg[kt][ct], acc[ct], 0, 0, 0);
                    // D layout: col = lane&15, row = quad*4 + reg  (m89-verified)
                    const int rbase = mh * 64 + rt * 16 + quad * 4;
                    #pragma unroll
                    for (int ct = 0; ct < 4; ++ct)
                        #pragma unroll
                        for (int rg = 0; rg < 4; ++rg)
                            zpart[(rbase + rg) * ZSTR + (ct * 16 + l15) * 4 + kq] = acc[ct][rg];
                }
            }
        }
        __syncthreads();                     // zpart complete for this step

        if (tv) {
            // ---- fused reduce + gates: thread -> (row gr, h-cols ct4*4..+3) ----
            float hv[4];
            #pragma unroll
            for (int jj = 0; jj < 4; ++jj) {
                float z[4];
                #pragma unroll
                for (int g = 0; g < 4; ++g) {
                    const f32x4 v = *(const f32x4*)&zpart[gr * ZSTR + (ct4 * 16 + g * 4 + jj) * 4];
                    float zz = v[0] + v[1];
                    if (t > 0) zz += v[2] + v[3];
                    z[g] = zz;
                }
                float zi = clampz(z[0] + bz[0][jj]);
                float zf = clampz(z[1] + bz[1][jj]);
                float zg = clampz(z[2] + bz[2][jj]);
                float zo = clampz(z[3] + bz[3][jj]);
                float cp = (t == 0) ? 0.0f : cS[jj];
                float cn = sigm(zf) * cp + sigm(zi) * ssign(zg);
                cS[jj] = cn;
                hv[jj] = sigm(zo) * ssign(cn);
            }
            // packed write-through stores (device-coherent; never dirty in L2)
            const int col = j0 + ct4 * 4;
            unsigned int pk0 = (unsigned int)f2b(hv[0]) | ((unsigned int)f2b(hv[1]) << 16);
            unsigned int pk1 = (unsigned int)f2b(hv[2]) | ((unsigned int)f2b(hv[3]) << 16);
            unsigned int* hp = (unsigned int*)&Hl[(size_t)t * BB * UU + (size_t)gr * UU + col];
            __hip_atomic_store(hp,     pk0, __ATOMIC_RELAXED, __HIP_MEMORY_SCOPE_AGENT);
            __hip_atomic_store(hp + 1, pk1, __ATOMIC_RELAXED, __HIP_MEMORY_SCOPE_AGENT);
            if (layer == 2 && t == TT - 1) {
                size_t o = (size_t)dir * BB * UU + (size_t)gr * UU + col;
                #pragma unroll
                for (int jj = 0; jj < 4; ++jj)
                    __hip_atomic_store(&p.hf[o + jj], hv[jj],
                                       __ATOMIC_RELAXED, __HIP_MEMORY_SCOPE_AGENT);
            }
        }
        gsync_dir(p, dirbase, eidx, isagg, ++gen);
    }

    gsync_all(p, dirbase, eidx, isagg, ++gen);   // both dirs' hf complete before head

    // ---------------- head: block b handles batch row b (all fp32) ----------------
    if (blk < BB) {
        const int b = blk;
        if (tid < 256) {
            const float* h0 = p.hf + (size_t)b * UU;
            const float* h1 = p.hf + (size_t)BB * UU + (size_t)b * UU;
            float acc = ld_f(p.d0b, tid, f32);
            #pragma unroll 8
            for (int k = 0; k < UU; ++k) {
                float a = 0.5f * (h0[k] + h1[k]);
                acc = fmaf(a, ld_f(p.d0W, (size_t)k * 256 + tid, f32), acc);
            }
            acc = fminf(fmaxf(acc, -1e6f), 1e6f);
            float x = (acc - ld_f(p.bn_mean, tid, f32))
                      * rsqrtf(fmaxf(ld_f(p.bn_var, tid, f32), 0.0f) + 1e-3f)
                      * ld_f(p.bn_gamma, tid, f32) + ld_f(p.bn_beta, tid, f32);
            float al = ld_f(p.alpha, tid, f32);
            hact[tid] = (x > 0.f) ? x : al * x;
        }
        __syncthreads();
        if (tid < 7) {
            float s = ld_f(p.d1b, tid, f32);
            #pragma unroll 8
            for (int k = 0; k < 256; ++k)
                s = fmaf(hact[k], ld_f(p.d1W, k * 7 + tid, f32), s);
            lgts[tid] = fminf(fmaxf(s, -1e6f), 1e6f);
        }
        __syncthreads();
        if (tid == 0) {
            float mx = lgts[0];
            for (int j = 1; j < 7; ++j) mx = fmaxf(mx, lgts[j]);
            float ex[7]; float sum = 0.f;
            for (int j = 0; j < 7; ++j) { ex[j] = __expf(lgts[j] - mx); sum += ex[j]; }
            float inv = 1.0f / sum;
            for (int j = 0; j < 7; ++j) p.out[b * 7 + j] = ex[j] * inv;
        }
    }
}

extern "C" void kernel_launch(void* const* d_in, const int* in_sizes, int n_in,
                              void* d_out, int out_size, void* d_ws, size_t ws_size,
                              hipStream_t stream) {
    (void)in_sizes; (void)n_in; (void)out_size;

    P p;
    p.ids = (const int*)d_in[0];
    p.emb = d_in[1];
    for (int l = 0; l < 3; ++l) {
        p.Wm[0][l] = d_in[2 + l * 3];
        p.Um[0][l] = d_in[3 + l * 3];
        p.bm[0][l] = d_in[4 + l * 3];
        p.Wm[1][l] = d_in[11 + l * 3];
        p.Um[1][l] = d_in[12 + l * 3];
        p.bm[1][l] = d_in[13 + l * 3];
    }
    p.d0W      = d_in[20];
    p.d0b      = d_in[21];
    p.bn_gamma = d_in[22];
    p.bn_beta  = d_in[23];
    p.bn_mean  = d_in[24];
    p.bn_var   = d_in[25];
    p.alpha    = d_in[26];
    p.d1W      = d_in[27];
    p.d1b      = d_in[28];

    char* base = (ws_size >= NEED_WS || g_pool == nullptr) ? (char*)d_ws : (char*)g_pool;
    const size_t OFF_X  = 8192;                                        // flags@0, epoch@4096
    const size_t OFF_H  = OFF_X + (size_t)TT * BB * EMBP * 2;          // +10,485,760
    const size_t OFF_HF = OFF_H + (size_t)3 * 2 * TT * BB * UU * 2;    // +100,663,296
    p.flags = (unsigned int*)base;
    p.epoch = (unsigned int*)(base + 4096);
    p.X     = (unsigned short*)(base + OFF_X);
    p.H     = (unsigned short*)(base + OFF_H);
    p.hf    = (float*)(base + OFF_HF);
    p.out   = (float*)d_out;

    hipMemsetAsync(base, 0, 8192, stream);   // flags+epoch; rest write-before-read
    hipLaunchKernelGGL(bilstm_persistent, dim3(NBLK), dim3(NTHR), 0, stream, p);
}